// Round 7
// baseline (357.432 us; speedup 1.0000x reference)
//
#include <hip/hip_runtime.h>
#include <stdint.h>

using fx4   = __attribute__((ext_vector_type(4))) float;
using half8 = __attribute__((ext_vector_type(8))) _Float16;

__device__ __forceinline__ ushort f2h(float x) {
  _Float16 h = (_Float16)x;
  union { _Float16 hv; ushort u; } v; v.hv = h;
  return v.u;
}

__device__ __forceinline__ void gload_lds16(const ushort* g, ushort* l) {
  __builtin_amdgcn_global_load_lds(
      (__attribute__((address_space(1))) const void*)g,
      (__attribute__((address_space(3))) void*)l, 16, 0, 0);
}

// Soft barrier: LDS-visibility only (lgkmcnt drain + raw s_barrier).  Global
// loads / global_load_lds DMAs stay in flight across it (R5-validated).
__device__ __forceinline__ void soft_barrier() {
  asm volatile("s_waitcnt lgkmcnt(0)" ::: "memory");
  __builtin_amdgcn_s_barrier();
  asm volatile("" ::: "memory");
}

#define MFMA16(a, b, c) __builtin_amdgcn_mfma_f32_16x16x32_f16(a, b, c, 0, 0, 0)

// Shared GEMM body (R0 structure: single-buffer, 2 barriers/K-step — the R6
// dbuf variant measured neutral).  C[m][n] = sum_k A[m][k]*B[n][k].
// flags: 1=relu, 2=store fp16 row-major,
//        16 = V-panel store: VT[(row>>5)*16384 + col*32 + (row&31)]
//        32 = KT panels (col<256, granule-XOR pre-swizzle for the attn LDS
//             reader) + Qm row-major (col>=256, via C2)
__device__ __forceinline__ void gemm_body(
    const ushort* __restrict__ A, int lda,
    const ushort* __restrict__ B, int ldb,
    const float* __restrict__ bias,
    void* __restrict__ C, int ldc,
    int K, int flags, int bx, int by,
    ushort* As, ushort* Bs, ushort* __restrict__ C2 = nullptr)
{
  const int tid  = threadIdx.x;
  const int lane = tid & 63;
  const int wave = tid >> 6;
  const int wm   = (wave >> 1) * 64;
  const int wn   = (wave & 1) * 64;
  const long long bm = (long long)by * 128;
  const long long bn = (long long)bx * 128;

  const int srow = tid >> 2;
  const int skq  = (tid & 3) * 8;
  const ushort* a0 = A + (bm + srow) * lda + skq;
  const ushort* a1 = a0 + 64LL * lda;
  const ushort* b0 = B + (bn + srow) * ldb + skq;
  const ushort* b1 = b0 + 64LL * ldb;
  ushort* lA0 = &As[tid * 8];
  ushort* lA1 = &As[2048 + tid * 8];
  ushort* lB0 = &Bs[tid * 8];
  ushort* lB1 = &Bs[2048 + tid * 8];

  fx4 acc[4][4] = {};
  const ushort* ap = &As[(wm + (lane & 15)) * 32 + (lane >> 4) * 8];
  const ushort* bp = &Bs[(wn + (lane & 15)) * 32 + (lane >> 4) * 8];

  for (int k0 = 0; k0 < K; k0 += 32) {
    gload_lds16(a0, lA0);
    gload_lds16(a1, lA1);
    gload_lds16(b0, lB0);
    gload_lds16(b1, lB1);
    a0 += 32; a1 += 32; b0 += 32; b1 += 32;
    __syncthreads();
    half8 af[4], bv[4];
#pragma unroll
    for (int t = 0; t < 4; ++t) {
      af[t] = *(const half8*)(ap + t * 16 * 32);
      bv[t] = *(const half8*)(bp + t * 16 * 32);
    }
#pragma unroll
    for (int i = 0; i < 4; ++i)
#pragma unroll
      for (int j = 0; j < 4; ++j)
        acc[i][j] = MFMA16(af[i], bv[j], acc[i][j]);
    __syncthreads();
  }

  const int col0 = (int)bn + wn + (lane & 15);
  const int row0 = (int)bm + wm + ((lane >> 4) << 2);

  if (flags & 16) {        // VT panel store: [panel][d 512][tok 32]
    ushort* Ch = (ushort*)C;
#pragma unroll
    for (int j = 0; j < 4; ++j) {
      const int col = col0 + j * 16;
      const float bvv = bias ? bias[col] : 0.0f;
#pragma unroll
      for (int i = 0; i < 4; ++i) {
        const int row = row0 + i * 16;
        ushort4 o;
        o.x = f2h(acc[i][j][0] + bvv);
        o.y = f2h(acc[i][j][1] + bvv);
        o.z = f2h(acc[i][j][2] + bvv);
        o.w = f2h(acc[i][j][3] + bvv);
        *(ushort4*)(Ch + (long long)(row >> 5) * 16384 + (long long)col * 32 + (row & 31)) = o;
      }
    }
    return;
  }

  if (flags & 32) {        // KT panels [p][dc 8][tok 32][32 swz] + Qm row-major
    ushort* KTp = (ushort*)C;
#pragma unroll
    for (int j = 0; j < 4; ++j) {
      const int col = col0 + j * 16;
      const float bvv = bias ? bias[col] : 0.0f;
#pragma unroll
      for (int i = 0; i < 4; ++i) {
        const int row = row0 + i * 16;
#pragma unroll
        for (int r = 0; r < 4; ++r) {
          const float v = acc[i][j][r] + bvv;
          if (col < 256) {
            const int tok = row + r;
            const int kk  = col & 31;
            // physical 16B-granule = logical_granule ^ (tok&3): makes the
            // attn LDS ds_read_b128 2-way (free) instead of 8-way conflicted.
            KTp[(long long)(tok >> 5) * 8192 + (col >> 5) * 1024 +
                (tok & 31) * 32 + ((((kk >> 3) ^ (tok & 3)) << 3) | (kk & 7))] = f2h(v);
          } else {
            C2[(long long)(row + r) * 256 + (col - 256)] = f2h(v);
          }
        }
      }
    }
    return;
  }

  float*  Cf = (float*)C;
  ushort* Ch = (ushort*)C;
#pragma unroll
  for (int j = 0; j < 4; ++j) {
    const int col = col0 + j * 16;
    const float bvv = bias ? bias[col] : 0.0f;
#pragma unroll
    for (int i = 0; i < 4; ++i) {
      const long long row = row0 + i * 16;
#pragma unroll
      for (int r = 0; r < 4; ++r) {
        float v = acc[i][j][r] + bvv;
        if (flags & 1) v = fmaxf(v, 0.0f);
        if (flags & 2) Ch[(row + r) * ldc + col] = f2h(v);
        else           Cf[(row + r) * ldc + col] = v;
      }
    }
  }
}

__global__ __launch_bounds__(256)
void gemm_bt(const ushort* __restrict__ A, int lda, long long sA,
             const ushort* __restrict__ B, int ldb, long long sB,
             const float* __restrict__ bias,
             void* __restrict__ C, int ldc, long long sC,
             int K, int flags)
{
  __shared__ ushort As[128 * 32];
  __shared__ ushort Bs[128 * 32];
  const int z = blockIdx.z;
  void* Cz = (flags & 2) ? (void*)((ushort*)C + (long long)z * sC)
                         : (void*)((float*)C + (long long)z * sC);
  gemm_body(A + (long long)z * sA, lda, B + (long long)z * sB, ldb, bias,
            Cz, ldc, K, flags, blockIdx.x, blockIdx.y, As, Bs);
}

// z=0: VT panels = (H[:,:1024] @ We2 + be2)  ; z=1: KT panels (swz) + Qm
__global__ __launch_bounds__(256)
void gemm2_pair(const ushort* __restrict__ H, const ushort* __restrict__ W2c,
                const float* __restrict__ be2, const float* __restrict__ bk2,
                ushort* __restrict__ VT, ushort* __restrict__ KT,
                ushort* __restrict__ Qm)
{
  __shared__ ushort As[128 * 32];
  __shared__ ushort Bs[128 * 32];
  if (blockIdx.z == 0)
    gemm_body(H, 2048, W2c, 1024, be2, VT, 0, 1024, 16,
              blockIdx.x, blockIdx.y, As, Bs);
  else
    gemm_body(H + 1024, 2048, W2c + 524288, 1024, bk2, KT, 0, 1024, 32,
              blockIdx.x, blockIdx.y, As, Bs, Qm);
}

// Single-pass flash attention, QBLK=64, 512 thr / 8 waves, 1 block/CU.
// Round-7 = R3's K-dedup with the VGPR cap fixed: __launch_bounds__(512,1)
// (NOT (512,2): 2nd arg = min waves/EU -> VGPR cap 128 -> the R3/R6 spills).
// - K tile (64 KB) DMA'd to LDS once per CU, double-buffered; prefetch of
//   t+1 issued at iteration TOP -> a full iteration of hiding; per-CU VMEM
//   stream 256->192 KB/iter (kills the qw-pair K duplication).
// - Q fragments in registers (frees Qs -> K dbuf fits: LDS 152.8 KB dynamic).
// - K LDS reads granule-XOR swizzled (writer pre-swizzles KT): 2-way (free).
// - Soft barriers + explicit vmcnt(8) before B2 retires the 8 K-DMAs for
//   cross-wave visibility; V loads stay in flight (split 8 pre-B1 / 8
//   post-B2 to cap peak VGPR ~235).
__global__ __launch_bounds__(512, 1)
void attn_fused(const ushort* __restrict__ KT, const ushort* __restrict__ VT,
                const ushort* __restrict__ Qm, float* __restrict__ out)
{
  extern __shared__ char smem[];
  ushort* Kb     = (ushort*)smem;             // [2][4 panel][8 dc][32 tok][32 swz] = 131072 B
  ushort* Ps     = (ushort*)(smem + 131072);  // [kc 4][64 q][40] = 20480 B
  float*  rmax   = (float*)(smem + 151552);   // [tw 4][64 q] = 1024 B
  float*  alphaA = (float*)(smem + 152576);   // 256 B
  float*  lred   = rmax;                      // alias: epilogue only

  const int tid  = threadIdx.x;
  const int lane = tid & 63;
  const int w    = tid >> 6;
  const int c    = lane & 15;
  const int q4   = lane >> 4;
  const int qw   = w >> 2;       // 0..1
  const int tw   = w & 3;        // 0..3
  const int dw   = w * 64;       // d-slice base
  const int z    = blockIdx.x;   // batch -> XCD locality
  const long long tb = (long long)z * 2048;
  const long long pbase = (long long)z * 64;   // first 32-tok panel of batch
  const int q0   = blockIdx.y * 64;
  const int swz  = (q4 ^ (c & 3)) << 3;        // matches gemm2's KT granule swizzle

  // hoist Q a-frags to registers (reused by all 16 iterations)
  half8 aq[2][8];
#pragma unroll
  for (int i = 0; i < 2; ++i)
#pragma unroll
    for (int dc = 0; dc < 8; ++dc)
      aq[i][dc] = *(const half8*)(Qm + (tb + q0 + qw * 32 + i * 16 + c) * 256 + dc * 32 + q4 * 8);

  // prologue: DMA K tile 0 into buffer 0 (64 KB, 8x 16B per thread)
  {
    const ushort* src = KT + pbase * 8192;
#pragma unroll
    for (int i = 0; i < 8; ++i)
      gload_lds16(src + (i * 512 + tid) * 8, Kb + (i * 512 + tid) * 8);
  }
  __syncthreads();   // full barrier: drains DMA -> K0 + visible to all waves

  float m_reg[2][4], l_part[2][4];
#pragma unroll
  for (int i = 0; i < 2; ++i)
#pragma unroll
    for (int r = 0; r < 4; ++r) { m_reg[i][r] = -3.0e38f; l_part[i][r] = 0.0f; }
  fx4 o[4][4] = {};

  int cur = 0;
  for (int t0 = 0; t0 < 2048; t0 += 128) {
    const long long pt = pbase + (t0 >> 5);
    // ---- prefetch NEXT K tile at iteration top (hidden under whole iter) ----
    {
      const long long ptn = pbase + (((t0 + 128) & 2047) >> 5);
      const ushort* src = KT + ptn * 8192;
      ushort* dst = Kb + (cur ^ 1) * 32768;
#pragma unroll
      for (int i = 0; i < 8; ++i)
        gload_lds16(src + (i * 512 + tid) * 8, dst + (i * 512 + tid) * 8);
    }
    asm volatile("" ::: "memory");
    // ---- QK: K b-frags from LDS (swizzled, conflict-free), Q from regs ----
    const ushort* kp = Kb + cur * 32768 + tw * 8192;
    fx4 s[2][2] = {};
#pragma unroll
    for (int dc = 0; dc < 8; ++dc) {
      const half8 b0 = *(const half8*)(kp + dc * 1024 + c * 32 + swz);
      const half8 b1 = *(const half8*)(kp + dc * 1024 + (16 + c) * 32 + swz);
      s[0][0] = MFMA16(aq[0][dc], b0, s[0][0]); s[0][1] = MFMA16(aq[0][dc], b1, s[0][1]);
      s[1][0] = MFMA16(aq[1][dc], b0, s[1][0]); s[1][1] = MFMA16(aq[1][dc], b1, s[1][1]);
    }
    // ---- issue V b-frag loads for kc=0,1 (consumed post-B2) ----
    half8 vb01[2][4];
#pragma unroll
    for (int kc = 0; kc < 2; ++kc)
#pragma unroll
      for (int n = 0; n < 4; ++n)
        vb01[kc][n] = *(const half8*)(VT + (pt + kc) * 16384 +
                                      (dw + n * 16 + c) * 32 + q4 * 8);
    // ---- local row max over this wave's 32 tok ----
#pragma unroll
    for (int i = 0; i < 2; ++i) {
      fx4 rm;
#pragma unroll
      for (int r = 0; r < 4; ++r) rm[r] = fmaxf(s[i][0][r], s[i][1][r]);
#pragma unroll
      for (int off = 1; off < 16; off <<= 1)
#pragma unroll
        for (int r = 0; r < 4; ++r) rm[r] = fmaxf(rm[r], __shfl_xor(rm[r], off, 64));
      if (c == 0) {
#pragma unroll
        for (int r = 0; r < 4; ++r)
          rmax[tw * 64 + qw * 32 + i * 16 + q4 * 4 + r] = rm[r];
      }
    }
    soft_barrier();   // B1: rmax ready (DMA + vb01 stay in flight)
    // ---- per-thread softmax update for own 8 q-rows (replicated regs) ----
#pragma unroll
    for (int i = 0; i < 2; ++i)
#pragma unroll
      for (int r = 0; r < 4; ++r) {
        const int q = qw * 32 + i * 16 + q4 * 4 + r;
        const float mo = m_reg[i][r];
        float mn = fmaxf(fmaxf(rmax[q], rmax[64 + q]),
                         fmaxf(rmax[128 + q], rmax[192 + q]));
        mn = fmaxf(mn, mo);
        m_reg[i][r] = mn;
        const float a  = __expf(mo - mn);
        const float e0 = __expf(s[i][0][r] - mn);
        const float e1 = __expf(s[i][1][r] - mn);
        l_part[i][r] = a * l_part[i][r] + e0 + e1;
        Ps[tw * 2560 + q * 40 + c]      = f2h(e0);
        Ps[tw * 2560 + q * 40 + 16 + c] = f2h(e1);
        if (tw == 0 && c == 0) alphaA[q] = a;
      }
    // retire the 8 K-DMAs (oldest outstanding) so B2 establishes cross-wave
    // visibility of Kb[cur^1]; vb01 (newer) may remain in flight.
    asm volatile("s_waitcnt vmcnt(8)" ::: "memory");
    soft_barrier();   // B2: Ps + alphaA + K(t+1) visible
    // ---- O rescale; issue vb kc=2,3; PV ----
#pragma unroll
    for (int i4 = 0; i4 < 4; ++i4)
#pragma unroll
      for (int r = 0; r < 4; ++r) {
        const float aqr = alphaA[i4 * 16 + q4 * 4 + r];
#pragma unroll
        for (int n = 0; n < 4; ++n) o[i4][n][r] *= aqr;
      }
    half8 vb23[2][4];
#pragma unroll
    for (int kc = 0; kc < 2; ++kc)
#pragma unroll
      for (int n = 0; n < 4; ++n)
        vb23[kc][n] = *(const half8*)(VT + (pt + 2 + kc) * 16384 +
                                      (dw + n * 16 + c) * 32 + q4 * 8);
#pragma unroll
    for (int kc = 0; kc < 4; ++kc) {
      half8 pa[4];
#pragma unroll
      for (int i4 = 0; i4 < 4; ++i4)
        pa[i4] = *(const half8*)(Ps + kc * 2560 + (i4 * 16 + c) * 40 + q4 * 8);
#pragma unroll
      for (int i4 = 0; i4 < 4; ++i4)
#pragma unroll
        for (int n = 0; n < 4; ++n)
          o[i4][n] = MFMA16(pa[i4], (kc < 2 ? vb01[kc][n] : vb23[kc - 2][n]),
                            o[i4][n]);
    }
    cur ^= 1;
  }

  // ---- epilogue: finalize l, normalize, store ----
#pragma unroll
  for (int i = 0; i < 2; ++i) {
    fx4 lv;
#pragma unroll
    for (int r = 0; r < 4; ++r) lv[r] = l_part[i][r];
#pragma unroll
    for (int off = 1; off < 16; off <<= 1)
#pragma unroll
      for (int r = 0; r < 4; ++r) lv[r] += __shfl_xor(lv[r], off, 64);
    if (c == 0) {
#pragma unroll
      for (int r = 0; r < 4; ++r)
        lred[tw * 64 + qw * 32 + i * 16 + q4 * 4 + r] = lv[r];
    }
  }
  soft_barrier();

  float* ob = out + (tb + q0) * 512 + dw;
#pragma unroll
  for (int i4 = 0; i4 < 4; ++i4)
#pragma unroll
    for (int r = 0; r < 4; ++r) {
      const int q = i4 * 16 + q4 * 4 + r;
      const float li = 1.0f / (lred[q] + lred[64 + q] + lred[128 + q] + lred[192 + q]);
#pragma unroll
      for (int n = 0; n < 4; ++n)
        ob[(long long)q * 512 + n * 16 + c] = o[i4][n][r] * li;
    }
}

// fp32 [R][C] -> fp16 [C][R], two inputs selected by blockIdx.z
__global__ __launch_bounds__(256)
void transpose_cast_w2(const float* __restrict__ in0, const float* __restrict__ in1,
                       ushort* __restrict__ out0, ushort* __restrict__ out1,
                       int R, int C) {
  __shared__ float tile[32][33];
  const float* in  = blockIdx.z ? in1 : in0;
  ushort*      outp = blockIdx.z ? out1 : out0;
  const int c0 = blockIdx.x * 32, r0 = blockIdx.y * 32;
  const int tx = threadIdx.x & 31, ty = threadIdx.x >> 5;
#pragma unroll
  for (int i = 0; i < 32; i += 8)
    tile[ty + i][tx] = in[(long long)(r0 + ty + i) * C + (c0 + tx)];
  __syncthreads();
#pragma unroll
  for (int i = 0; i < 32; i += 8)
    outp[(long long)(c0 + ty + i) * R + (r0 + tx)] = f2h(tile[tx][ty + i]);
}

__global__ __launch_bounds__(256)
void cast_f32_f16(const float* __restrict__ in, ushort* __restrict__ out) {
  const long long i = ((long long)blockIdx.x * 256 + threadIdx.x) * 4;
  const float4 v = *(const float4*)(in + i);
  ushort4 o;
  o.x = f2h(v.x); o.y = f2h(v.y); o.z = f2h(v.z); o.w = f2h(v.w);
  *(ushort4*)(out + i) = o;
}

__global__ __launch_bounds__(256)
void concat_bias(const float* __restrict__ b0, const float* __restrict__ b1,
                 float* __restrict__ out) {
  const int i = blockIdx.x * 256 + threadIdx.x;
  out[i] = (i < 1024) ? b0[i] : b1[i - 1024];
}

extern "C" void kernel_launch(void* const* d_in, const int* in_sizes, int n_in,
                              void* d_out, int out_size, void* d_ws, size_t ws_size,
                              hipStream_t stream) {
  (void)in_sizes; (void)n_in; (void)out_size; (void)ws_size;
  const float* x   = (const float*)d_in[0];
  const float* We1 = (const float*)d_in[1];
  const float* be1 = (const float*)d_in[2];
  const float* We2 = (const float*)d_in[3];
  const float* be2 = (const float*)d_in[4];
  const float* Wk1 = (const float*)d_in[5];
  const float* bk1 = (const float*)d_in[6];
  const float* Wk2 = (const float*)d_in[7];
  const float* bk2 = (const float*)d_in[8];
  float* out = (float*)d_out;
  char* ws = (char*)d_ws;

  ushort* Xb  = (ushort*)(ws + 0);            // 16.78 MB, dead after gemm1
  ushort* W2c = (ushort*)(ws + 0);            // 2 MB, written after gemm1
  ushort* H   = (ushort*)(ws + 16777216);     // 16384x2048 fp16 = 67.1 MB
  ushort* VT  = (ushort*)(ws + 83886080);     // 512 panels x [512 d][32 tok] = 16.78 MB
  ushort* KT  = (ushort*)(ws + 100663296);    // 512 panels x [8 dc][32 tok][32 swz] = 8.39 MB
  ushort* Qm  = (ushort*)(ws + 109051904);    // 16384x256 fp16 = 8.39 MB
  float*  b1c = (float*)(ws + 117440512);     // 2048 fp32
  ushort* W1c = (ushort*)(ws + 117448704);    // 2 MB

  cast_f32_f16<<<dim3(8192), 256, 0, stream>>>(x, Xb);
  transpose_cast_w2<<<dim3(32, 16, 2), 256, 0, stream>>>(We1, Wk1, W1c, W1c + 524288, 512, 1024);
  concat_bias<<<dim3(8), 256, 0, stream>>>(be1, bk1, b1c);

  // H = relu(x @ [We1|Wk1] + [be1|bk1])   [16384,2048]
  gemm_bt<<<dim3(16, 128, 1), 256, 0, stream>>>(Xb, 512, 0, W1c, 512, 0, b1c,
                                                H, 2048, 0, 512, 1 | 2);

  transpose_cast_w2<<<dim3(16, 32, 2), 256, 0, stream>>>(We2, Wk2, W2c, W2c + 524288, 1024, 512);

  // z=0: VT panels ; z=1: KT panels (swizzled) + Qm
  gemm2_pair<<<dim3(4, 128, 2), 256, 0, stream>>>(H, W2c, be2, bk2, VT, KT, Qm);

  // flash attention: 152832 B dynamic LDS (K dbuf 128K + Ps 20K + red 1.25K)
  hipFuncSetAttribute(reinterpret_cast<const void*>(attn_fused),
                      hipFuncAttributeMaxDynamicSharedMemorySize, 152832);
  attn_fused<<<dim3(8, 32), 512, 152832, stream>>>(KT, VT, Qm, out);
}

// Round 8
// 325.157 us; speedup vs baseline: 1.0993x; 1.0993x over previous
//
#include <hip/hip_runtime.h>
#include <stdint.h>

using fx4   = __attribute__((ext_vector_type(4))) float;
using half8 = __attribute__((ext_vector_type(8))) _Float16;

__device__ __forceinline__ ushort f2h(float x) {
  _Float16 h = (_Float16)x;
  union { _Float16 hv; ushort u; } v; v.hv = h;
  return v.u;
}

__device__ __forceinline__ void gload_lds16(const ushort* g, ushort* l) {
  __builtin_amdgcn_global_load_lds(
      (__attribute__((address_space(1))) const void*)g,
      (__attribute__((address_space(3))) void*)l, 16, 0, 0);
}

#define MFMA16(a, b, c) __builtin_amdgcn_mfma_f32_16x16x32_f16(a, b, c, 0, 0, 0)

// Shared GEMM body (R0-proven K-loop). C[m][n] = sum_k A[m][k]*B[n][k].
// flags: 1=relu, 2=store fp16 row-major (LDS-bounce coalesced epilogue, needs Cs),
//        16 = V-panel store: VT[(row>>5)*16384 + col*32 + (row&31)]
//        32 = KT panels (col<256) + Qm row-major (col>=256, via C2)
__device__ __forceinline__ void gemm_body(
    const ushort* __restrict__ A, int lda,
    const ushort* __restrict__ B, int ldb,
    const float* __restrict__ bias,
    void* __restrict__ C, int ldc,
    int K, int flags, int bx, int by,
    ushort* As, ushort* Bs,
    ushort* __restrict__ C2 = nullptr, ushort* Cs = nullptr)
{
  const int tid  = threadIdx.x;
  const int lane = tid & 63;
  const int wave = tid >> 6;
  const int wm   = (wave >> 1) * 64;
  const int wn   = (wave & 1) * 64;
  const long long bm = (long long)by * 128;
  const long long bn = (long long)bx * 128;

  const int srow = tid >> 2;
  const int skq  = (tid & 3) * 8;
  const ushort* a0 = A + (bm + srow) * lda + skq;
  const ushort* a1 = a0 + 64LL * lda;
  const ushort* b0 = B + (bn + srow) * ldb + skq;
  const ushort* b1 = b0 + 64LL * ldb;
  ushort* lA0 = &As[tid * 8];
  ushort* lA1 = &As[2048 + tid * 8];
  ushort* lB0 = &Bs[tid * 8];
  ushort* lB1 = &Bs[2048 + tid * 8];

  fx4 acc[4][4] = {};
  const ushort* ap = &As[(wm + (lane & 15)) * 32 + (lane >> 4) * 8];
  const ushort* bp = &Bs[(wn + (lane & 15)) * 32 + (lane >> 4) * 8];

  for (int k0 = 0; k0 < K; k0 += 32) {
    gload_lds16(a0, lA0);
    gload_lds16(a1, lA1);
    gload_lds16(b0, lB0);
    gload_lds16(b1, lB1);
    a0 += 32; a1 += 32; b0 += 32; b1 += 32;
    __syncthreads();
    half8 af[4], bv[4];
#pragma unroll
    for (int t = 0; t < 4; ++t) {
      af[t] = *(const half8*)(ap + t * 16 * 32);
      bv[t] = *(const half8*)(bp + t * 16 * 32);
    }
#pragma unroll
    for (int i = 0; i < 4; ++i)
#pragma unroll
      for (int j = 0; j < 4; ++j)
        acc[i][j] = MFMA16(af[i], bv[j], acc[i][j]);
    __syncthreads();
  }

  const int col0 = (int)bn + wn + (lane & 15);
  const int row0 = (int)bm + wm + ((lane >> 4) << 2);

  if (flags & 2) {
    // Row-major fp16 store via LDS bounce: old path was 64 scalar 2B stores
    // per thread (32B partial-line segments, ~50% write efficiency on 67 MB).
    // Two passes of 64 rows through Cs (16 KB); each thread then writes one
    // fully-coalesced 64B chunk per row-quarter.
    ushort* Ch = (ushort*)C;
    const int row = tid >> 2, qd = tid & 3;
#pragma unroll
    for (int p = 0; p < 2; ++p) {
      if ((wm >> 6) == p) {
#pragma unroll
        for (int j = 0; j < 4; ++j) {
          const int col = col0 + j * 16;
          const float bvv = bias ? bias[col] : 0.0f;
#pragma unroll
          for (int i = 0; i < 4; ++i)
#pragma unroll
            for (int r = 0; r < 4; ++r) {
              float v = acc[i][j][r] + bvv;
              if (flags & 1) v = fmaxf(v, 0.0f);
              Cs[(i * 16 + ((lane >> 4) << 2) + r) * 128 + wn + j * 16 + (lane & 15)] = f2h(v);
            }
        }
      }
      __syncthreads();
      const ushort* src = Cs + row * 128 + qd * 32;
      ushort* dst = Ch + (bm + p * 64 + row) * ldc + bn + qd * 32;
#pragma unroll
      for (int k = 0; k < 4; ++k)
        *(uint4*)(dst + k * 8) = *(const uint4*)(src + k * 8);
      __syncthreads();
    }
    return;
  }

  if (flags & 16) {        // VT panel store: [panel][d 512][tok 32]
    ushort* Ch = (ushort*)C;
#pragma unroll
    for (int j = 0; j < 4; ++j) {
      const int col = col0 + j * 16;
      const float bvv = bias ? bias[col] : 0.0f;
#pragma unroll
      for (int i = 0; i < 4; ++i) {
        const int row = row0 + i * 16;
        ushort4 o;
        o.x = f2h(acc[i][j][0] + bvv);
        o.y = f2h(acc[i][j][1] + bvv);
        o.z = f2h(acc[i][j][2] + bvv);
        o.w = f2h(acc[i][j][3] + bvv);
        *(ushort4*)(Ch + (long long)(row >> 5) * 16384 + (long long)col * 32 + (row & 31)) = o;
      }
    }
    return;
  }

  if (flags & 32) {        // KT panels [p][dc 8][tok 32][32] + Qm row-major
    ushort* KTp = (ushort*)C;
#pragma unroll
    for (int j = 0; j < 4; ++j) {
      const int col = col0 + j * 16;
      const float bvv = bias ? bias[col] : 0.0f;
#pragma unroll
      for (int i = 0; i < 4; ++i) {
        const int row = row0 + i * 16;
#pragma unroll
        for (int r = 0; r < 4; ++r) {
          const float v = acc[i][j][r] + bvv;
          if (col < 256) {
            const int tok = row + r;
            KTp[(long long)(tok >> 5) * 8192 + (col >> 5) * 1024 +
                (tok & 31) * 32 + (col & 31)] = f2h(v);
          } else {
            C2[(long long)(row + r) * 256 + (col - 256)] = f2h(v);
          }
        }
      }
    }
    return;
  }

  float* Cf = (float*)C;
#pragma unroll
  for (int j = 0; j < 4; ++j) {
    const int col = col0 + j * 16;
    const float bvv = bias ? bias[col] : 0.0f;
#pragma unroll
    for (int i = 0; i < 4; ++i) {
      const long long row = row0 + i * 16;
#pragma unroll
      for (int r = 0; r < 4; ++r) {
        float v = acc[i][j][r] + bvv;
        if (flags & 1) v = fmaxf(v, 0.0f);
        Cf[(row + r) * ldc + col] = v;
      }
    }
  }
}

// XCD-aware tile swizzle: dispatch round-robins linear block id across the 8
// XCD L2s, so blocks sharing an A row-panel (same by) scatter across all 8
// XCDs and the panel is fetched 8x.  Remap (bijective, ny % 8 == 0) so each
// XCD owns a contiguous by-range with ALL bx for those rows -> each A/H panel
// lands in exactly one XCD's L2.
__device__ __forceinline__ void xcd_swizzle(int& bx, int& by) {
  const int nx = gridDim.x, ny = gridDim.y;
  const int d  = blockIdx.x + nx * blockIdx.y;
  const int py = ny >> 3;            // row-panels per XCD
  const int q  = d >> 3;
  by = (d & 7) * py + (q % py);
  bx = q / py;
}

__global__ __launch_bounds__(256)
void gemm_bt(const ushort* __restrict__ A, int lda, long long sA,
             const ushort* __restrict__ B, int ldb, long long sB,
             const float* __restrict__ bias,
             void* __restrict__ C, int ldc, long long sC,
             int K, int flags)
{
  __shared__ ushort As[128 * 32];
  __shared__ ushort Bs[128 * 32];
  __shared__ ushort Cs[64 * 128];
  int bx, by;
  xcd_swizzle(bx, by);
  const int z = blockIdx.z;
  void* Cz = (flags & 2) ? (void*)((ushort*)C + (long long)z * sC)
                         : (void*)((float*)C + (long long)z * sC);
  gemm_body(A + (long long)z * sA, lda, B + (long long)z * sB, ldb, bias,
            Cz, ldc, K, flags, bx, by, As, Bs, nullptr, Cs);
}

// z=0: VT panels = (H[:,:1024] @ We2 + be2)  ; z=1: KT panels + Qm
__global__ __launch_bounds__(256)
void gemm2_pair(const ushort* __restrict__ H, const ushort* __restrict__ W2c,
                const float* __restrict__ be2, const float* __restrict__ bk2,
                ushort* __restrict__ VT, ushort* __restrict__ KT,
                ushort* __restrict__ Qm)
{
  __shared__ ushort As[128 * 32];
  __shared__ ushort Bs[128 * 32];
  int bx, by;
  xcd_swizzle(bx, by);                 // per-z: z stride 512 = 0 mod 8
  if (blockIdx.z == 0)
    gemm_body(H, 2048, W2c, 1024, be2, VT, 0, 1024, 16,
              bx, by, As, Bs);
  else
    gemm_body(H + 1024, 2048, W2c + 524288, 1024, bk2, KT, 0, 1024, 32,
              bx, by, As, Bs, Qm);
}

// Single-pass flash attention — exact R0 structure (best measured: 100.8 us).
// Seven rounds of scheduling/occupancy/register variants (R1-R7) were all
// neutral or worse; the kernel sits at a multi-pipe work equilibrium at
// 2 waves/SIMD.  Block = (batch, 64-q tile), 512 thr / 8 waves.
__global__ __launch_bounds__(512, 2)
void attn_fused(const ushort* __restrict__ KT, const ushort* __restrict__ VT,
                const ushort* __restrict__ Qm, float* __restrict__ out)
{
  __shared__ ushort Qs[20480];   // [dc 8][64 q][40]
  __shared__ ushort Ps[10240];   // [kc 4][64 q][40]
  __shared__ float  rmax[256];   // [tw 4][64 q]
  __shared__ float  mstate[64];
  __shared__ float  mnewA[64];
  __shared__ float  alphaA[64];  // reused as linv in epilogue
  __shared__ float  lred[256];   // [tw 4][64 q]

  const int tid  = threadIdx.x;
  const int lane = tid & 63;
  const int w    = tid >> 6;
  const int c    = lane & 15;
  const int q4   = lane >> 4;
  const int qw   = w >> 2;       // 0..1
  const int tw   = w & 3;        // 0..3
  const int dw   = w * 64;       // d-slice base
  const int z    = blockIdx.x;   // batch -> XCD locality
  const long long tb = (long long)z * 2048;
  const long long pbase = (long long)z * 64;   // first 32-tok panel of batch
  const int q0   = blockIdx.y * 64;

  // stage Q-tile 64x256 into padded LDS from Qm
#pragma unroll
  for (int p = 0; p < 4; ++p) {
    const int cu  = p * 512 + tid;       // 0..2047
    const int row = cu >> 5;             // 0..63
    const int kch = cu & 31;
    const int dc  = kch >> 2, qg = kch & 3;
    const half8 v = *(const half8*)(Qm + (tb + q0 + row) * 256 + dc * 32 + qg * 8);
    *(half8*)(Qs + dc * 2560 + row * 40 + qg * 8) = v;
  }
  if (tid < 64) mstate[tid] = -3.0e38f;
  __syncthreads();

  float l_part[2][4] = {};
  fx4 o[4][4] = {};

  for (int t0 = 0; t0 < 2048; t0 += 128) {
    const long long pt = pbase + (t0 >> 5);
    // ---- hoist all 16 K b-frags (coalesced panel loads), then QK MFMAs ----
    half8 kb[2][8];
    const ushort* kp = KT + (pt + tw) * 8192;
#pragma unroll
    for (int dc = 0; dc < 8; ++dc) {
      kb[0][dc] = *(const half8*)(kp + dc * 1024 + c * 32 + q4 * 8);
      kb[1][dc] = *(const half8*)(kp + dc * 1024 + (16 + c) * 32 + q4 * 8);
    }
    fx4 s[2][2] = {};
#pragma unroll
    for (int dc = 0; dc < 8; ++dc) {
      const half8 a0 = *(const half8*)(Qs + dc * 2560 + (qw * 32 + c) * 40 + q4 * 8);
      const half8 a1 = *(const half8*)(Qs + dc * 2560 + (qw * 32 + 16 + c) * 40 + q4 * 8);
      s[0][0] = MFMA16(a0, kb[0][dc], s[0][0]); s[0][1] = MFMA16(a0, kb[1][dc], s[0][1]);
      s[1][0] = MFMA16(a1, kb[0][dc], s[1][0]); s[1][1] = MFMA16(a1, kb[1][dc], s[1][1]);
    }
    // ---- issue all 16 V b-frag loads NOW (coalesced panel loads) ----
    half8 vb[4][4];
#pragma unroll
    for (int kc = 0; kc < 4; ++kc)
#pragma unroll
      for (int n = 0; n < 4; ++n)
        vb[kc][n] = *(const half8*)(VT + (pt + kc) * 16384 +
                                    (dw + n * 16 + c) * 32 + q4 * 8);
    // ---- local row max over this wave's 32 tok ----
#pragma unroll
    for (int i = 0; i < 2; ++i) {
      fx4 rm;
#pragma unroll
      for (int r = 0; r < 4; ++r) rm[r] = fmaxf(s[i][0][r], s[i][1][r]);
#pragma unroll
      for (int off = 1; off < 16; off <<= 1)
#pragma unroll
        for (int r = 0; r < 4; ++r) rm[r] = fmaxf(rm[r], __shfl_xor(rm[r], off, 64));
      if (c == 0) {
#pragma unroll
        for (int r = 0; r < 4; ++r)
          rmax[tw * 64 + qw * 32 + i * 16 + q4 * 4 + r] = rm[r];
      }
    }
    __syncthreads();
    if (w == 0) {   // lane = q row
      const float mo = mstate[lane];
      float mn = fmaxf(fmaxf(rmax[lane], rmax[64 + lane]),
                       fmaxf(rmax[128 + lane], rmax[192 + lane]));
      mn = fmaxf(mn, mo);
      mnewA[lane]  = mn;
      alphaA[lane] = __expf(mo - mn);
      mstate[lane] = mn;
    }
    __syncthreads();
    // ---- P = exp(s - m) fp16 -> LDS ; l update ; O rescale ----
#pragma unroll
    for (int i = 0; i < 2; ++i)
#pragma unroll
      for (int r = 0; r < 4; ++r) {
        const int q = qw * 32 + i * 16 + q4 * 4 + r;
        const float mn = mnewA[q];
        const float e0 = __expf(s[i][0][r] - mn);
        const float e1 = __expf(s[i][1][r] - mn);
        l_part[i][r] = alphaA[q] * l_part[i][r] + e0 + e1;
        Ps[tw * 2560 + q * 40 + c]      = f2h(e0);
        Ps[tw * 2560 + q * 40 + 16 + c] = f2h(e1);
      }
#pragma unroll
    for (int i4 = 0; i4 < 4; ++i4)
#pragma unroll
      for (int r = 0; r < 4; ++r) {
        const float aq = alphaA[i4 * 16 + q4 * 4 + r];
#pragma unroll
        for (int n = 0; n < 4; ++n) o[i4][n][r] *= aq;
      }
    __syncthreads();
    // ---- PV: a-frags from Ps, V b-frags already in registers ----
#pragma unroll
    for (int kc = 0; kc < 4; ++kc) {
      half8 pa[4];
#pragma unroll
      for (int i4 = 0; i4 < 4; ++i4)
        pa[i4] = *(const half8*)(Ps + kc * 2560 + (i4 * 16 + c) * 40 + q4 * 8);
#pragma unroll
      for (int i4 = 0; i4 < 4; ++i4)
#pragma unroll
        for (int n = 0; n < 4; ++n)
          o[i4][n] = MFMA16(pa[i4], vb[kc][n], o[i4][n]);
    }
  }

  // ---- epilogue: finalize l, normalize, store ----
#pragma unroll
  for (int i = 0; i < 2; ++i) {
    fx4 lv;
#pragma unroll
    for (int r = 0; r < 4; ++r) lv[r] = l_part[i][r];
#pragma unroll
    for (int off = 1; off < 16; off <<= 1)
#pragma unroll
      for (int r = 0; r < 4; ++r) lv[r] += __shfl_xor(lv[r], off, 64);
    if (c == 0) {
#pragma unroll
      for (int r = 0; r < 4; ++r)
        lred[tw * 64 + qw * 32 + i * 16 + q4 * 4 + r] = lv[r];
    }
  }
  __syncthreads();
  if (w == 0)
    alphaA[lane] = 1.0f / (lred[lane] + lred[64 + lane] + lred[128 + lane] + lred[192 + lane]);
  __syncthreads();

  float* ob = out + (tb + q0) * 512 + dw;
#pragma unroll
  for (int i4 = 0; i4 < 4; ++i4)
#pragma unroll
    for (int r = 0; r < 4; ++r) {
      const int q = i4 * 16 + q4 * 4 + r;
      const float li = alphaA[q];
#pragma unroll
      for (int n = 0; n < 4; ++n)
        ob[(long long)q * 512 + n * 16 + c] = o[i4][n][r] * li;
    }
}

// fp32 [R][C] -> fp16 [C][R], two inputs selected by blockIdx.z
__global__ __launch_bounds__(256)
void transpose_cast_w2(const float* __restrict__ in0, const float* __restrict__ in1,
                       ushort* __restrict__ out0, ushort* __restrict__ out1,
                       int R, int C) {
  __shared__ float tile[32][33];
  const float* in  = blockIdx.z ? in1 : in0;
  ushort*      outp = blockIdx.z ? out1 : out0;
  const int c0 = blockIdx.x * 32, r0 = blockIdx.y * 32;
  const int tx = threadIdx.x & 31, ty = threadIdx.x >> 5;
#pragma unroll
  for (int i = 0; i < 32; i += 8)
    tile[ty + i][tx] = in[(long long)(r0 + ty + i) * C + (c0 + tx)];
  __syncthreads();
#pragma unroll
  for (int i = 0; i < 32; i += 8)
    outp[(long long)(c0 + ty + i) * R + (r0 + tx)] = f2h(tile[tx][ty + i]);
}

__global__ __launch_bounds__(256)
void cast_f32_f16(const float* __restrict__ in, ushort* __restrict__ out) {
  const long long i = ((long long)blockIdx.x * 256 + threadIdx.x) * 4;
  const float4 v = *(const float4*)(in + i);
  ushort4 o;
  o.x = f2h(v.x); o.y = f2h(v.y); o.z = f2h(v.z); o.w = f2h(v.w);
  *(ushort4*)(out + i) = o;
}

__global__ __launch_bounds__(256)
void concat_bias(const float* __restrict__ b0, const float* __restrict__ b1,
                 float* __restrict__ out) {
  const int i = blockIdx.x * 256 + threadIdx.x;
  out[i] = (i < 1024) ? b0[i] : b1[i - 1024];
}

extern "C" void kernel_launch(void* const* d_in, const int* in_sizes, int n_in,
                              void* d_out, int out_size, void* d_ws, size_t ws_size,
                              hipStream_t stream) {
  (void)in_sizes; (void)n_in; (void)out_size; (void)ws_size;
  const float* x   = (const float*)d_in[0];
  const float* We1 = (const float*)d_in[1];
  const float* be1 = (const float*)d_in[2];
  const float* We2 = (const float*)d_in[3];
  const float* be2 = (const float*)d_in[4];
  const float* Wk1 = (const float*)d_in[5];
  const float* bk1 = (const float*)d_in[6];
  const float* Wk2 = (const float*)d_in[7];
  const float* bk2 = (const float*)d_in[8];
  float* out = (float*)d_out;
  char* ws = (char*)d_ws;

  ushort* Xb  = (ushort*)(ws + 0);            // 16.78 MB, dead after gemm1
  ushort* W2c = (ushort*)(ws + 0);            // 2 MB, written after gemm1
  ushort* H   = (ushort*)(ws + 16777216);     // 16384x2048 fp16 = 67.1 MB
  ushort* VT  = (ushort*)(ws + 83886080);     // 512 panels x [512 d][32 tok] = 16.78 MB
  ushort* KT  = (ushort*)(ws + 100663296);    // 512 panels x [8 dc][32 tok][32] = 8.39 MB
  ushort* Qm  = (ushort*)(ws + 109051904);    // 16384x256 fp16 = 8.39 MB
  float*  b1c = (float*)(ws + 117440512);     // 2048 fp32
  ushort* W1c = (ushort*)(ws + 117448704);    // 2 MB

  cast_f32_f16<<<dim3(8192), 256, 0, stream>>>(x, Xb);
  transpose_cast_w2<<<dim3(32, 16, 2), 256, 0, stream>>>(We1, Wk1, W1c, W1c + 524288, 512, 1024);
  concat_bias<<<dim3(8), 256, 0, stream>>>(be1, bk1, b1c);

  // H = relu(x @ [We1|Wk1] + [be1|bk1])   [16384,2048]
  gemm_bt<<<dim3(16, 128, 1), 256, 0, stream>>>(Xb, 512, 0, W1c, 512, 0, b1c,
                                                H, 2048, 0, 512, 1 | 2);

  transpose_cast_w2<<<dim3(16, 32, 2), 256, 0, stream>>>(We2, Wk2, W2c, W2c + 524288, 1024, 512);

  // z=0: VT panels ; z=1: KT panels + Qm
  gemm2_pair<<<dim3(4, 128, 2), 256, 0, stream>>>(H, W2c, be2, bk2, VT, KT, Qm);

  // flash attention: grid x=batch (XCD-local), y=64-q tile, 512 thr
  attn_fused<<<dim3(8, 32), 512, 0, stream>>>(KT, VT, Qm, out);
}